// Round 1
// baseline (592.112 us; speedup 1.0000x reference)
//
#include <hip/hip_runtime.h>

#define DD 256
#define HH 8
#define CC 32

// ---------------- utility kernels ----------------
__global__ void k_zero_i(int* p, int n){ int i=blockIdx.x*blockDim.x+threadIdx.x; if(i<n) p[i]=0; }
__global__ void k_zero_f(float* p, int n){ int i=blockIdx.x*blockDim.x+threadIdx.x; if(i<n) p[i]=0.f; }

// ---------------- CSR build (graph is static across both layers) ----------------
__global__ void k_count(const int* __restrict__ dstE, int E, int N, int* cnt){
  int e=blockIdx.x*blockDim.x+threadIdx.x;
  if(e<E+N){ int d=(e<E)? dstE[e] : (e-E); atomicAdd(&cnt[d],1); }
}

__global__ __launch_bounds__(1024) void k_scan(const int* __restrict__ cnt, int N, int* row_off, int* cursor){
  __shared__ int part[1024];
  int t=threadIdx.x;
  int chunk=(N+1023)>>10;
  int s=0;
  for(int j=0;j<chunk;j++){ int i=t*chunk+j; if(i<N) s+=cnt[i]; }
  part[t]=s; __syncthreads();
  for(int off=1; off<1024; off<<=1){
    int v=(t>=off)? part[t-off]:0;
    __syncthreads();
    part[t]+=v;
    __syncthreads();
  }
  int run=(t==0)?0:part[t-1];
  for(int j=0;j<chunk;j++){ int i=t*chunk+j; if(i<N){ row_off[i]=run; cursor[i]=run; run+=cnt[i]; } }
  if(t==1023) row_off[N]=part[1023];
}

__global__ void k_fill(const int* __restrict__ srcE, const int* __restrict__ dstE, int E, int N,
                       int* cursor, int* eid, int* esrc){
  int e=blockIdx.x*blockDim.x+threadIdx.x;
  if(e>=E+N) return;
  int s,d;
  if(e<E){ s=srcE[e]; d=dstE[e]; } else { s=e-E; d=s; }
  int pos=atomicAdd(&cursor[d],1);
  eid[pos]=e; esrc[pos]=s;
}

// ---------------- per-layer small precompute ----------------
// wd_as[k*8+h] = sum_c Wd[k, h*32+c]*a_s[h,c]   (so a_i = x @ wd_as)
// v_e[k*8+h]   = sum_c We[k, h*32+c]*ae[h,c]    (edge-attr logit folded)
// t_a[t*8+h]   = sum_c te[t, h*32+c]*ae[h,c]    (edge-type logit folded)
__global__ void k_pre(const float* __restrict__ Wd, const float* __restrict__ as_,
                      const float* __restrict__ We, const float* __restrict__ ae,
                      const float* __restrict__ te,
                      float* wd_as, float* v_e, float* t_a){
  int t=threadIdx.x;
  for(int idx=t; idx<DD*HH; idx+=256){
    int k=idx>>3, h=idx&7;
    const float* w=&Wd[k*DD+h*CC]; const float* a=&as_[h*CC];
    float s=0;
    #pragma unroll
    for(int c=0;c<CC;c++) s+=w[c]*a[c];
    wd_as[idx]=s;
  }
  for(int idx=t; idx<16*HH; idx+=256){
    int k=idx>>3, h=idx&7;
    const float* w=&We[k*DD+h*CC]; const float* a=&ae[h*CC];
    float s=0;
    #pragma unroll
    for(int c=0;c<CC;c++) s+=w[c]*a[c];
    v_e[idx]=s;
  }
  for(int idx=t; idx<7*HH; idx+=256){
    int k=idx>>3, h=idx&7;
    const float* w=&te[k*DD+h*CC]; const float* a=&ae[h*CC];
    float s=0;
    #pragma unroll
    for(int c=0;c<CC;c++) s+=w[c]*a[c];
    t_a[idx]=s;
  }
}

// ---------------- f32 GEMM  C[N,256] = A[N,256] @ B[256,256] (+bias) ----------------
// 64x64 block tile, 4x4 microtile per thread, 256 threads.
template<bool BIAS>
__global__ __launch_bounds__(256) void k_gemm64(const float* __restrict__ A, const float* __restrict__ B,
                        const float* __restrict__ b1, const float* __restrict__ b2,
                        float* __restrict__ Cm, int N){
  __shared__ float Ast[16][68];   // [k][row], padded stride 68 (16B-aligned, conflict-free)
  __shared__ float Bs[16][64];    // [k][col]
  int tid=threadIdx.x;
  int row0=blockIdx.y*64, col0=blockIdx.x*64;
  int tx=tid&15, ty=tid>>4;
  float acc[4][4];
  #pragma unroll
  for(int i=0;i<4;i++)
    #pragma unroll
    for(int j=0;j<4;j++) acc[i][j]=0.f;
  int ar=tid>>2, akq=tid&3;       // A stage: row ar (0..63), k-quad akq
  int bk=tid>>4, bc=(tid&15)*4;   // B stage: k bk (0..15), col quad bc
  for(int kt=0; kt<DD; kt+=16){
    float4 av;
    int arow=row0+ar;
    if(arow<N) av=*(const float4*)&A[(size_t)arow*DD + kt + akq*4];
    else av=make_float4(0.f,0.f,0.f,0.f);
    float4 bv=*(const float4*)&B[(size_t)(kt+bk)*DD + col0 + bc];
    __syncthreads();
    Ast[akq*4+0][ar]=av.x; Ast[akq*4+1][ar]=av.y; Ast[akq*4+2][ar]=av.z; Ast[akq*4+3][ar]=av.w;
    *(float4*)&Bs[bk][bc]=bv;
    __syncthreads();
    #pragma unroll
    for(int k=0;k<16;k++){
      float4 a4=*(const float4*)&Ast[k][ty*4];
      float4 b4=*(const float4*)&Bs[k][tx*4];
      float aa[4]={a4.x,a4.y,a4.z,a4.w};
      float bb[4]={b4.x,b4.y,b4.z,b4.w};
      #pragma unroll
      for(int i=0;i<4;i++)
        #pragma unroll
        for(int j=0;j<4;j++) acc[i][j]+=aa[i]*bb[j];
    }
  }
  #pragma unroll
  for(int i=0;i<4;i++){
    int row=row0+ty*4+i;
    if(row>=N) continue;
    int col=col0+tx*4;
    float4 v=make_float4(acc[i][0],acc[i][1],acc[i][2],acc[i][3]);
    if(BIAS){
      v.x+=b1[col+0]+b2[col+0]; v.y+=b1[col+1]+b2[col+1];
      v.z+=b1[col+2]+b2[col+2]; v.w+=b1[col+3]+b2[col+3];
    }
    *(float4*)&Cm[(size_t)row*DD+col]=v;
  }
}

// ---------------- per-node attention scalars ----------------
// a_i[n,h] = x[n,:] @ wd_as[:,h];  a_j[n,h] = sum_c ys[n,h*32+c]*a_d[h,c]
__global__ void k_aiaj(const float* __restrict__ xin, const float* __restrict__ ys,
                       const float* __restrict__ wd_as, const float* __restrict__ ad,
                       float* a_i, float* a_j, int N){
  int idx=blockIdx.x*blockDim.x+threadIdx.x;
  if(idx>=N*HH) return;
  int n=idx>>3, h=idx&7;
  const float* xr=&xin[(size_t)n*DD];
  float s=0.f;
  for(int k=0;k<DD;k++) s+=xr[k]*wd_as[k*8+h];
  a_i[idx]=s;
  const float* yr=&ys[(size_t)n*DD+h*CC];
  const float* adh=&ad[h*CC];
  float t=0.f;
  #pragma unroll
  for(int c=0;c<CC;c++) t+=yr[c]*adh[c];
  a_j[idx]=t;
}

// ---------------- edge logits (leaky-relu'd) ----------------
__global__ void k_edge(const int* __restrict__ srcE, const int* __restrict__ dstE,
                       const float* __restrict__ ea, const int* __restrict__ et,
                       const float* __restrict__ a_i, const float* __restrict__ a_j,
                       const float* __restrict__ v_e, const float* __restrict__ t_a,
                       float* __restrict__ alpha, int E, int N){
  int e=blockIdx.x*blockDim.x+threadIdx.x;
  if(e>=E+N) return;
  int s,d,ty;
  float eattr[16];
  if(e<E){
    s=srcE[e]; d=dstE[e]; ty=et[e];
    #pragma unroll
    for(int k=0;k<16;k++) eattr[k]=ea[(size_t)e*16+k];
  }else{
    s=e-E; d=s; ty=6;
    #pragma unroll
    for(int k=0;k<16;k++) eattr[k]=1.f;
  }
  const float* ai=&a_i[(size_t)d*8];
  const float* aj=&a_j[(size_t)s*8];
  #pragma unroll
  for(int h=0;h<8;h++){
    float v=ai[h]+aj[h]+t_a[ty*8+h];
    #pragma unroll
    for(int k=0;k<16;k++) v+=eattr[k]*v_e[k*8+h];
    alpha[(size_t)e*8+h] = (v>=0.f)? v : 0.2f*v;
  }
}

// ---------------- segment softmax + message aggregation (one block per node) ----------------
__global__ __launch_bounds__(256) void k_agg(const int* __restrict__ row_off, const int* __restrict__ eid,
                      const int* __restrict__ esrc, const float* __restrict__ alpha,
                      const float* __restrict__ ys, float* __restrict__ agg){
  int n=blockIdx.x, tid=threadIdx.x;
  int beg=row_off[n], end=row_off[n+1];
  int deg=end-beg;
  __shared__ float red[256];
  __shared__ float m[8], ssum[8];
  __shared__ float wch[64][8];
  __shared__ int sch[64];
  // phase 1: per-head max over incoming edges
  int h=tid&7, j=tid>>3;
  float mx=-3e38f;
  for(int i=j;i<deg;i+=32) mx=fmaxf(mx, alpha[(size_t)eid[beg+i]*8+h]);
  red[tid]=mx; __syncthreads();
  #pragma unroll
  for(int off=128; off>=8; off>>=1){
    if(tid<off) red[tid]=fmaxf(red[tid],red[tid+off]);
    __syncthreads();
  }
  if(tid<8){ m[tid]=red[tid]; ssum[tid]=0.f; }
  __syncthreads();
  // phase 2/3 chunked: weights -> LDS, sum, weighted feature gather
  float acc=0.f;
  int fh=tid>>5;          // head of this feature column
  for(int base=0;base<deg;base+=64){
    int cnt=min(64,deg-base);
    for(int idx=tid; idx<cnt*8; idx+=256){
      int i=idx>>3, hh=idx&7;
      int e=eid[beg+base+i];
      float w=__expf(alpha[(size_t)e*8+hh]-m[hh]);
      wch[i][hh]=w;
      if(hh==0) sch[i]=esrc[beg+base+i];
    }
    __syncthreads();
    if(tid<8){
      float s2=ssum[tid];
      for(int i=0;i<cnt;i++) s2+=wch[i][tid];
      ssum[tid]=s2;
    }
    for(int i=0;i<cnt;i++)
      acc += wch[i][fh]*ys[(size_t)sch[i]*DD+tid];
    __syncthreads();
  }
  agg[(size_t)n*DD+tid]=acc/(ssum[fh]+1e-16f);
}

// ---------------- LayerNorm + residual (one block per row) ----------------
__global__ __launch_bounds__(256) void k_ln_res(const float* __restrict__ z, const float* __restrict__ xin,
                         const float* __restrict__ lg, const float* __restrict__ lb,
                         float* __restrict__ hout, int N){
  __shared__ float red[256];
  __shared__ float stats[2];
  int n=blockIdx.x, tid=threadIdx.x;
  float v=z[(size_t)n*DD+tid];
  red[tid]=v; __syncthreads();
  #pragma unroll
  for(int off=128; off>0; off>>=1){ if(tid<off) red[tid]+=red[tid+off]; __syncthreads(); }
  if(tid==0) stats[0]=red[0]*(1.f/DD);
  __syncthreads();
  float mu=stats[0], d=v-mu;
  red[tid]=d*d; __syncthreads();
  #pragma unroll
  for(int off=128; off>0; off>>=1){ if(tid<off) red[tid]+=red[tid+off]; __syncthreads(); }
  if(tid==0) stats[1]=rsqrtf(red[0]*(1.f/DD)+1e-5f);
  __syncthreads();
  hout[(size_t)n*DD+tid]=d*stats[1]*lg[tid]+lb[tid]+xin[(size_t)n*DD+tid];
}

// ---------------- BatchNorm stats / finalize / apply ----------------
__global__ __launch_bounds__(256) void k_bnstat(const float* __restrict__ hm, float* colsum, float* colsq, int N){
  int col=threadIdx.x;
  int rows_per=(N+gridDim.x-1)/gridDim.x;
  int r0=blockIdx.x*rows_per, r1=min(N,r0+rows_per);
  float s=0.f,q=0.f;
  for(int r=r0;r<r1;r++){ float v=hm[(size_t)r*DD+col]; s+=v; q+=v*v; }
  atomicAdd(&colsum[col],s);
  atomicAdd(&colsq[col],q);
}

__global__ void k_bnfin(const float* __restrict__ colsum, const float* __restrict__ colsq,
                        const float* __restrict__ g, const float* __restrict__ b,
                        float* scale, float* shift, int N){
  int c=threadIdx.x;
  float inv=1.f/(float)N;
  float mu=colsum[c]*inv;
  float var=colsq[c]*inv - mu*mu;
  float sc=g[c]*rsqrtf(var+1e-5f);
  scale[c]=sc;
  shift[c]=b[c]-mu*sc;
}

// out = relu(h*scale + shift [+ res])
__global__ void k_bnapply(const float* __restrict__ hm, const float* __restrict__ scale,
                          const float* __restrict__ shift, const float* __restrict__ res,
                          float* __restrict__ outp, int total){
  int i=blockIdx.x*blockDim.x+threadIdx.x;
  if(i>=total) return;
  int c=i&(DD-1);
  float v=hm[i]*scale[c]+shift[c];
  if(res) v+=res[i];
  outp[i]=fmaxf(v,0.f);
}

// ---------------- host-side layer driver ----------------
static void run_layer(hipStream_t stream, int N, int E,
    const float* xin, const int* srcE, const int* dstE, const float* ea, const int* et,
    const float* Ws, const float* Wd, const float* as_, const float* ad,
    const float* We, const float* ae, const float* te,
    const float* Wo, const float* bo, const float* bv,
    const float* lg, const float* lb, const float* bng, const float* bnb,
    const int* row_off, const int* eid, const int* esrc,
    float* ys, float* agg, float* alphaBuf, float* a_i, float* a_j,
    float* wd_as, float* v_e, float* t_a,
    float* colsum, float* colsq, float* scl, float* shf,
    float* hbuf, const float* resFinal, float* outp)
{
  int Etot=E+N;
  k_pre<<<1,256,0,stream>>>(Wd,as_,We,ae,te,wd_as,v_e,t_a);
  dim3 gg(4,(N+63)/64);
  k_gemm64<false><<<gg,256,0,stream>>>(xin,Ws,nullptr,nullptr,ys,N);
  k_aiaj<<<(N*HH+255)/256,256,0,stream>>>(xin,ys,wd_as,ad,a_i,a_j,N);
  k_edge<<<(Etot+255)/256,256,0,stream>>>(srcE,dstE,ea,et,a_i,a_j,v_e,t_a,alphaBuf,E,N);
  k_agg<<<N,256,0,stream>>>(row_off,eid,esrc,alphaBuf,ys,agg);
  // z = agg @ Wo + bo + b   (reuse ys as z buffer; ys no longer needed)
  k_gemm64<true><<<gg,256,0,stream>>>(agg,Wo,bo,bv,ys,N);
  k_ln_res<<<N,256,0,stream>>>(ys,xin,lg,lb,hbuf,N);
  k_zero_f<<<2,256,0,stream>>>(colsum,512);   // colsum & colsq contiguous
  k_bnstat<<<256,256,0,stream>>>(hbuf,colsum,colsq,N);
  k_bnfin<<<1,256,0,stream>>>(colsum,colsq,bng,bnb,scl,shf,N);
  k_bnapply<<<(N*DD+255)/256,256,0,stream>>>(hbuf,scl,shf,resFinal,outp,N*DD);
}

extern "C" void kernel_launch(void* const* d_in, const int* in_sizes, int n_in,
                              void* d_out, int out_size, void* d_ws, size_t ws_size,
                              hipStream_t stream) {
  const float* x  = (const float*)d_in[0];
  const int*   ei = (const int*)d_in[1];
  const float* ea = (const float*)d_in[2];
  const int*   et = (const int*)d_in[3];
  int N = in_sizes[0]/DD;
  int E = in_sizes[3];
  int Etot = E+N;
  const int* srcE = ei;
  const int* dstE = ei + E;

  // layer weights
  const float* Ws1=(const float*)d_in[4];  const float* Wd1=(const float*)d_in[5];
  const float* as1=(const float*)d_in[6];  const float* ad1=(const float*)d_in[7];
  const float* We1=(const float*)d_in[8];  const float* ae1=(const float*)d_in[9];
  const float* te1=(const float*)d_in[10]; const float* Wo1=(const float*)d_in[11];
  const float* bo1=(const float*)d_in[12]; const float* b1 =(const float*)d_in[13];
  const float* lg1=(const float*)d_in[14]; const float* lb1=(const float*)d_in[15];
  const float* Ws2=(const float*)d_in[16]; const float* Wd2=(const float*)d_in[17];
  const float* as2=(const float*)d_in[18]; const float* ad2=(const float*)d_in[19];
  const float* We2=(const float*)d_in[20]; const float* ae2=(const float*)d_in[21];
  const float* te2=(const float*)d_in[22]; const float* Wo2=(const float*)d_in[23];
  const float* bo2=(const float*)d_in[24]; const float* b2 =(const float*)d_in[25];
  const float* lg2=(const float*)d_in[26]; const float* lb2=(const float*)d_in[27];
  const float* bng1=(const float*)d_in[28]; const float* bnb1=(const float*)d_in[29];
  const float* bng2=(const float*)d_in[30]; const float* bnb2=(const float*)d_in[31];

  // workspace carve (256B-aligned chunks)
  char* p=(char*)d_ws;
  auto alloc=[&](size_t bytes)->void*{ void* r=(void*)p; p+=(bytes+255)&~(size_t)255; return r; };
  float* ys    =(float*)alloc((size_t)N*DD*4);
  float* agg   =(float*)alloc((size_t)N*DD*4);
  float* xout1 =(float*)alloc((size_t)N*DD*4);
  float* alphaB=(float*)alloc((size_t)Etot*HH*4);
  float* a_i   =(float*)alloc((size_t)N*HH*4);
  float* a_j   =(float*)alloc((size_t)N*HH*4);
  float* wd_as =(float*)alloc(DD*HH*4);
  float* v_e   =(float*)alloc(16*HH*4);
  float* t_a   =(float*)alloc(7*HH*4);
  float* colsum=(float*)alloc(256*4);   // colsq must directly follow (zeroed together)
  float* colsq =(float*)alloc(256*4);
  float* scl   =(float*)alloc(256*4);
  float* shf   =(float*)alloc(256*4);
  int* cnt     =(int*)alloc((size_t)N*4);
  int* row_off =(int*)alloc((size_t)(N+1)*4);
  int* cursor  =(int*)alloc((size_t)N*4);
  int* eid     =(int*)alloc((size_t)Etot*4);
  int* esrc    =(int*)alloc((size_t)Etot*4);
  float* hbuf  =(float*)d_out;   // pre-BN buffer lives in d_out (overwritten by final pass)

  // ---- CSR by destination (shared by both layers) ----
  k_zero_i<<<(N+255)/256,256,0,stream>>>(cnt,N);
  k_count<<<(Etot+255)/256,256,0,stream>>>(dstE,E,N,cnt);
  k_scan<<<1,1024,0,stream>>>(cnt,N,row_off,cursor);
  k_fill<<<(Etot+255)/256,256,0,stream>>>(srcE,dstE,E,N,cursor,eid,esrc);

  // ---- layer 1 ----
  run_layer(stream,N,E, x,srcE,dstE,ea,et,
            Ws1,Wd1,as1,ad1,We1,ae1,te1,Wo1,bo1,b1,lg1,lb1,bng1,bnb1,
            row_off,eid,esrc,
            ys,agg,alphaB,a_i,a_j,wd_as,v_e,t_a,colsum,colsq,scl,shf,
            hbuf,nullptr,xout1);

  // ---- layer 2 (input xout1; final residual = original x, relu) ----
  run_layer(stream,N,E, xout1,srcE,dstE,ea,et,
            Ws2,Wd2,as2,ad2,We2,ae2,te2,Wo2,bo2,b2,lg2,lb2,bng2,bnb2,
            row_off,eid,esrc,
            ys,agg,alphaB,a_i,a_j,wd_as,v_e,t_a,colsum,colsq,scl,shf,
            hbuf,x,(float*)d_out);
}

// Round 2
// 480.893 us; speedup vs baseline: 1.2313x; 1.2313x over previous
//
#include <hip/hip_runtime.h>

#define DD 256
#define HH 8
#define CC 32

typedef __attribute__((ext_vector_type(8))) short short8;
typedef __attribute__((ext_vector_type(4))) float f32x4;

static __device__ __forceinline__ unsigned short f2b(float f){
  unsigned u = __float_as_uint(f);
  u = u + 0x7FFFu + ((u >> 16) & 1u);          // RNE
  return (unsigned short)(u >> 16);
}
static __device__ __forceinline__ float b2f(unsigned short s){
  return __uint_as_float(((unsigned)s) << 16);
}

// ---------------- utility ----------------
__global__ void k_zero_i(int* p, int n){ int i=blockIdx.x*blockDim.x+threadIdx.x; if(i<n) p[i]=0; }
__global__ void k_zero_f(float* p, int n){ int i=blockIdx.x*blockDim.x+threadIdx.x; if(i<n) p[i]=0.f; }

// ---------------- CSR build ----------------
__global__ void k_count(const int* __restrict__ dstE, int E, int N, int* cnt){
  int e=blockIdx.x*blockDim.x+threadIdx.x;
  if(e<E+N){ int d=(e<E)? dstE[e] : (e-E); atomicAdd(&cnt[d],1); }
}

__global__ __launch_bounds__(1024) void k_scan(const int* __restrict__ cnt, int N, int* row_off, int* cursor){
  __shared__ int part[1024];
  int t=threadIdx.x;
  int chunk=(N+1023)>>10;
  int s=0;
  for(int j=0;j<chunk;j++){ int i=t*chunk+j; if(i<N) s+=cnt[i]; }
  part[t]=s; __syncthreads();
  for(int off=1; off<1024; off<<=1){
    int v=(t>=off)? part[t-off]:0;
    __syncthreads();
    part[t]+=v;
    __syncthreads();
  }
  int run=(t==0)?0:part[t-1];
  for(int j=0;j<chunk;j++){ int i=t*chunk+j; if(i<N){ row_off[i]=run; cursor[i]=run; run+=cnt[i]; } }
  if(t==1023) row_off[N]=part[1023];
}

__global__ void k_fill(const int* __restrict__ srcE, const int* __restrict__ dstE, int E, int N,
                       int* cursor, int* eid, int* esrc){
  int e=blockIdx.x*blockDim.x+threadIdx.x;
  if(e>=E+N) return;
  int s,d;
  if(e<E){ s=srcE[e]; d=dstE[e]; } else { s=e-E; d=s; }
  int pos=atomicAdd(&cursor[d],1);
  eid[pos]=e; esrc[pos]=s;
}

// ---------------- weight transpose + bf16 convert: Wt[c][k] = W[k][c] ----------------
__global__ void k_cvt_wT(const float* __restrict__ W, unsigned short* __restrict__ Wt){
  int c=blockIdx.x, k=threadIdx.x;
  Wt[(size_t)c*DD+k] = f2b(W[(size_t)k*DD+c]);
}

// ---------------- folded logit weights ----------------
__global__ void k_pre(const float* __restrict__ Wd, const float* __restrict__ as_,
                      const float* __restrict__ We, const float* __restrict__ ae,
                      const float* __restrict__ te,
                      float* wd_as, float* v_e, float* t_a){
  int t=threadIdx.x;
  for(int idx=t; idx<DD*HH; idx+=256){
    int k=idx>>3, h=idx&7;
    const float* w=&Wd[k*DD+h*CC]; const float* a=&as_[h*CC];
    float s=0;
    #pragma unroll
    for(int c=0;c<CC;c++) s+=w[c]*a[c];
    wd_as[idx]=s;
  }
  for(int idx=t; idx<16*HH; idx+=256){
    int k=idx>>3, h=idx&7;
    const float* w=&We[k*DD+h*CC]; const float* a=&ae[h*CC];
    float s=0;
    #pragma unroll
    for(int c=0;c<CC;c++) s+=w[c]*a[c];
    v_e[idx]=s;
  }
  for(int idx=t; idx<7*HH; idx+=256){
    int k=idx>>3, h=idx&7;
    const float* w=&te[k*DD+h*CC]; const float* a=&ae[h*CC];
    float s=0;
    #pragma unroll
    for(int c=0;c<CC;c++) s+=w[c]*a[c];
    t_a[idx]=s;
  }
}

// ---------------- x -> bf16 + a_i = x @ wd_as ----------------
__global__ __launch_bounds__(256) void k_cvt_x(const float* __restrict__ xin, const float* __restrict__ wd_as,
                        unsigned short* __restrict__ xb, float* __restrict__ a_i, int N){
  __shared__ float red[DD*HH];     // [k][h] 8KB
  __shared__ float part[8][8];
  int n=blockIdx.x, tid=threadIdx.x;
  float v=xin[(size_t)n*DD+tid];
  xb[(size_t)n*DD+tid]=f2b(v);
  #pragma unroll
  for(int h=0;h<HH;h++) red[tid*HH+h]=v*wd_as[tid*HH+h];
  __syncthreads();
  if(tid<64){
    int h=tid&7, ch=tid>>3;
    float s=0.f;
    for(int k=ch*32;k<ch*32+32;k++) s+=red[k*HH+h];
    part[ch][h]=s;
  }
  __syncthreads();
  if(tid<8){
    float s=0.f;
    #pragma unroll
    for(int ch=0;ch<8;ch++) s+=part[ch][tid];
    a_i[(size_t)n*HH+tid]=s;
  }
}

// ---------------- a_j[n,h] = sum_c ys[n,32h+c]*ad[h,c] (ys bf16) ----------------
__global__ void k_aj(const unsigned short* __restrict__ ysb, const float* __restrict__ ad,
                     float* __restrict__ a_j, int N){
  int n=blockIdx.x, tid=threadIdx.x;
  float p=b2f(ysb[(size_t)n*DD+tid])*ad[tid];
  #pragma unroll
  for(int off=16;off>0;off>>=1) p+=__shfl_xor(p,off);
  if((tid&31)==0) a_j[(size_t)n*HH+(tid>>5)]=p;
}

// ---------------- bf16 MFMA GEMM: C[N,256] = A_bf16[N,256] @ B (Bt = B^T bf16) ----------------
// tile: BM=64 rows, BN=128 cols, BK=32. 4 waves; wave w: cols [32w,32w+32), all 64 rows.
// LDS granules (16B = 8 bf16): data (r,kc) at slot r*4 + (kc ^ ((r>>1)&3)).
template<bool OUTBF16, bool BIAS>
__global__ __launch_bounds__(256) void k_gemm_mfma(const unsigned short* __restrict__ A,
                                                   const unsigned short* __restrict__ Bt,
                                                   const float* __restrict__ bia1, const float* __restrict__ bia2,
                                                   void* __restrict__ Cout, int N){
  __shared__ char lds[4096 + 8192];   // As 64x32 bf16 (4KB) + Bs 128x32 bf16 (8KB)
  int tid=threadIdx.x;
  int w=tid>>6, l=tid&63;
  int row0=blockIdx.y*64, col0=blockIdx.x*128;

  // staging coords
  int sr=l>>2, skc=l&3;
  int arow=16*w+sr;                                  // tile-local A row
  int a_slot=arow*4+skc;
  int a_kc=skc^((arow>>1)&3);                        // source k-granule
  int grow=row0+arow;
  int bcol0=(2*w+0)*16+sr, bcol1=(2*w+1)*16+sr;      // tile-local B cols
  int b_slot0=bcol0*4+skc, b_slot1=bcol1*4+skc;
  int b_kc0=skc^((bcol0>>1)&3), b_kc1=skc^((bcol1>>1)&3);

  // read lane offset (same for A and B regions)
  int x15=l&15;
  int lp=x15*64 + ((l>>4)^((x15>>1)&3))*16;

  f32x4 acc[4][2];
  #pragma unroll
  for(int i=0;i<4;i++){ acc[i][0]=(f32x4)0.f; acc[i][1]=(f32x4)0.f; }

  const short8 zero8=(short8)0;
  for(int kt=0;kt<DD;kt+=32){
    short8 av = (grow<N) ? *(const short8*)&A[(size_t)grow*DD + kt + a_kc*8] : zero8;
    short8 bv0 = *(const short8*)&Bt[(size_t)(col0+bcol0)*DD + kt + b_kc0*8];
    short8 bv1 = *(const short8*)&Bt[(size_t)(col0+bcol1)*DD + kt + b_kc1*8];
    __syncthreads();
    *(short8*)(lds + a_slot*16) = av;
    *(short8*)(lds + 4096 + b_slot0*16) = bv0;
    *(short8*)(lds + 4096 + b_slot1*16) = bv1;
    __syncthreads();
    short8 af[4], bf[2];
    #pragma unroll
    for(int mf=0;mf<4;mf++) af[mf]=*(short8*)(lds + mf*1024 + lp);
    #pragma unroll
    for(int nf=0;nf<2;nf++) bf[nf]=*(short8*)(lds + 4096 + w*2048 + nf*1024 + lp);
    #pragma unroll
    for(int mf=0;mf<4;mf++)
      #pragma unroll
      for(int nf=0;nf<2;nf++)
        acc[mf][nf]=__builtin_amdgcn_mfma_f32_16x16x32_bf16(af[mf],bf[nf],acc[mf][nf],0,0,0);
  }

  // epilogue: C/D layout col=l&15, row=4*(l>>4)+rr
  int lcol=l&15, lrow4=(l>>4)*4;
  #pragma unroll
  for(int mf=0;mf<4;mf++){
    #pragma unroll
    for(int nf=0;nf<2;nf++){
      int col=col0 + 32*w + 16*nf + lcol;
      float badd = BIAS ? (bia1[col]+bia2[col]) : 0.f;
      #pragma unroll
      for(int rr=0;rr<4;rr++){
        int row=row0 + 16*mf + lrow4 + rr;
        if(row<N){
          float v=acc[mf][nf][rr]+badd;
          if(OUTBF16) ((unsigned short*)Cout)[(size_t)row*DD+col]=f2b(v);
          else        ((float*)Cout)[(size_t)row*DD+col]=v;
        }
      }
    }
  }
}

// ---------------- edge logits ----------------
__global__ void k_edge(const int* __restrict__ srcE, const int* __restrict__ dstE,
                       const float* __restrict__ ea, const int* __restrict__ et,
                       const float* __restrict__ a_i, const float* __restrict__ a_j,
                       const float* __restrict__ v_e, const float* __restrict__ t_a,
                       float* __restrict__ alpha, int E, int N){
  int e=blockIdx.x*blockDim.x+threadIdx.x;
  if(e>=E+N) return;
  int s,d,ty;
  float eattr[16];
  if(e<E){
    s=srcE[e]; d=dstE[e]; ty=et[e];
    #pragma unroll
    for(int k=0;k<16;k++) eattr[k]=ea[(size_t)e*16+k];
  }else{
    s=e-E; d=s; ty=6;
    #pragma unroll
    for(int k=0;k<16;k++) eattr[k]=1.f;
  }
  const float* ai=&a_i[(size_t)d*8];
  const float* aj=&a_j[(size_t)s*8];
  #pragma unroll
  for(int h=0;h<8;h++){
    float v=ai[h]+aj[h]+t_a[ty*8+h];
    #pragma unroll
    for(int k=0;k<16;k++) v+=eattr[k]*v_e[k*8+h];
    alpha[(size_t)e*8+h] = (v>=0.f)? v : 0.2f*v;
  }
}

// ---------------- segment softmax + aggregation (bf16 gather) ----------------
__global__ __launch_bounds__(256) void k_agg(const int* __restrict__ row_off, const int* __restrict__ eid,
                      const int* __restrict__ esrc, const float* __restrict__ alpha,
                      const unsigned short* __restrict__ ysb, unsigned short* __restrict__ aggb){
  int n=blockIdx.x, tid=threadIdx.x;
  int beg=row_off[n], end=row_off[n+1];
  int deg=end-beg;
  __shared__ float red[256];
  __shared__ float m[8], ssum[8];
  __shared__ float wch[64][8];
  __shared__ int sch[64];
  int h=tid&7, j=tid>>3;
  float mx=-3e38f;
  for(int i=j;i<deg;i+=32) mx=fmaxf(mx, alpha[(size_t)eid[beg+i]*8+h]);
  red[tid]=mx; __syncthreads();
  #pragma unroll
  for(int off=128; off>=8; off>>=1){
    if(tid<off) red[tid]=fmaxf(red[tid],red[tid+off]);
    __syncthreads();
  }
  if(tid<8){ m[tid]=red[tid]; ssum[tid]=0.f; }
  __syncthreads();
  float acc=0.f;
  int fh=tid>>5;
  for(int base=0;base<deg;base+=64){
    int cnt=min(64,deg-base);
    for(int idx=tid; idx<cnt*8; idx+=256){
      int i=idx>>3, hh=idx&7;
      int e=eid[beg+base+i];
      float wv=__expf(alpha[(size_t)e*8+hh]-m[hh]);
      wch[i][hh]=wv;
      if(hh==0) sch[i]=esrc[beg+base+i];
    }
    __syncthreads();
    if(tid<8){
      float s2=ssum[tid];
      for(int i=0;i<cnt;i++) s2+=wch[i][tid];
      ssum[tid]=s2;
    }
    for(int i=0;i<cnt;i++)
      acc += wch[i][fh]*b2f(ysb[(size_t)sch[i]*DD+tid]);
    __syncthreads();
  }
  aggb[(size_t)n*DD+tid]=f2b(acc/(ssum[fh]+1e-16f));
}

// ---------------- LayerNorm + residual ----------------
__global__ __launch_bounds__(256) void k_ln_res(const float* __restrict__ z, const float* __restrict__ xin,
                         const float* __restrict__ lg, const float* __restrict__ lb,
                         float* __restrict__ hout, int N){
  __shared__ float red[256];
  __shared__ float stats[2];
  int n=blockIdx.x, tid=threadIdx.x;
  float v=z[(size_t)n*DD+tid];
  red[tid]=v; __syncthreads();
  #pragma unroll
  for(int off=128; off>0; off>>=1){ if(tid<off) red[tid]+=red[tid+off]; __syncthreads(); }
  if(tid==0) stats[0]=red[0]*(1.f/DD);
  __syncthreads();
  float mu=stats[0], d=v-mu;
  red[tid]=d*d; __syncthreads();
  #pragma unroll
  for(int off=128; off>0; off>>=1){ if(tid<off) red[tid]+=red[tid+off]; __syncthreads(); }
  if(tid==0) stats[1]=rsqrtf(red[0]*(1.f/DD)+1e-5f);
  __syncthreads();
  hout[(size_t)n*DD+tid]=d*stats[1]*lg[tid]+lb[tid]+xin[(size_t)n*DD+tid];
}

// ---------------- BatchNorm ----------------
__global__ __launch_bounds__(256) void k_bnstat(const float* __restrict__ hm, float* colsum, float* colsq, int N){
  int col=threadIdx.x;
  int rows_per=(N+gridDim.x-1)/gridDim.x;
  int r0=blockIdx.x*rows_per, r1=min(N,r0+rows_per);
  float s=0.f,q=0.f;
  for(int r=r0;r<r1;r++){ float v=hm[(size_t)r*DD+col]; s+=v; q+=v*v; }
  atomicAdd(&colsum[col],s);
  atomicAdd(&colsq[col],q);
}

__global__ void k_bnfin(const float* __restrict__ colsum, const float* __restrict__ colsq,
                        const float* __restrict__ g, const float* __restrict__ b,
                        float* scale, float* shift, int N){
  int c=threadIdx.x;
  float inv=1.f/(float)N;
  float mu=colsum[c]*inv;
  float var=colsq[c]*inv - mu*mu;
  float sc=g[c]*rsqrtf(var+1e-5f);
  scale[c]=sc;
  shift[c]=b[c]-mu*sc;
}

__global__ void k_bnapply(const float* __restrict__ hm, const float* __restrict__ scale,
                          const float* __restrict__ shift, const float* __restrict__ res,
                          float* __restrict__ outp, int total){
  int i=blockIdx.x*blockDim.x+threadIdx.x;
  if(i>=total) return;
  int c=i&(DD-1);
  float v=hm[i]*scale[c]+shift[c];
  if(res) v+=res[i];
  outp[i]=fmaxf(v,0.f);
}

// ---------------- layer driver ----------------
static void run_layer(hipStream_t stream, int N, int E,
    const float* xin, const int* srcE, const int* dstE, const float* ea, const int* et,
    const unsigned short* WsbT, const float* Wd, const float* as_, const float* ad,
    const float* We, const float* ae, const float* te,
    const unsigned short* WobT, const float* bo, const float* bv,
    const float* lg, const float* lb, const float* bng, const float* bnb,
    const int* row_off, const int* eid, const int* esrc,
    unsigned short* xb, unsigned short* ysb, unsigned short* aggb,
    float* Sreg,                         // shared region: alpha then z
    float* a_i, float* a_j,
    float* wd_as, float* v_e, float* t_a,
    float* colsum, float* colsq, float* scl, float* shf,
    float* hbuf, const float* resFinal, float* outp)
{
  int Etot=E+N;
  float* alphaBuf=Sreg;
  float* zbuf=Sreg;
  dim3 gg(2,(N+63)/64);
  k_pre<<<1,256,0,stream>>>(Wd,as_,We,ae,te,wd_as,v_e,t_a);
  k_cvt_x<<<N,256,0,stream>>>(xin,wd_as,xb,a_i,N);
  k_gemm_mfma<true,false><<<gg,256,0,stream>>>(xb,WsbT,nullptr,nullptr,(void*)ysb,N);
  k_aj<<<N,256,0,stream>>>(ysb,ad,a_j,N);
  k_edge<<<(Etot+255)/256,256,0,stream>>>(srcE,dstE,ea,et,a_i,a_j,v_e,t_a,alphaBuf,E,N);
  k_agg<<<N,256,0,stream>>>(row_off,eid,esrc,alphaBuf,ysb,aggb);
  k_gemm_mfma<false,true><<<gg,256,0,stream>>>(aggb,WobT,bo,bv,(void*)zbuf,N);
  k_ln_res<<<N,256,0,stream>>>(zbuf,xin,lg,lb,hbuf,N);
  k_zero_f<<<2,256,0,stream>>>(colsum,512);
  k_bnstat<<<256,256,0,stream>>>(hbuf,colsum,colsq,N);
  k_bnfin<<<1,256,0,stream>>>(colsum,colsq,bng,bnb,scl,shf,N);
  k_bnapply<<<(N*DD+255)/256,256,0,stream>>>(hbuf,scl,shf,resFinal,outp,N*DD);
}

extern "C" void kernel_launch(void* const* d_in, const int* in_sizes, int n_in,
                              void* d_out, int out_size, void* d_ws, size_t ws_size,
                              hipStream_t stream) {
  const float* x  = (const float*)d_in[0];
  const int*   ei = (const int*)d_in[1];
  const float* ea = (const float*)d_in[2];
  const int*   et = (const int*)d_in[3];
  int N = in_sizes[0]/DD;
  int E = in_sizes[3];
  int Etot = E+N;
  const int* srcE = ei;
  const int* dstE = ei + E;

  const float* Ws1=(const float*)d_in[4];  const float* Wd1=(const float*)d_in[5];
  const float* as1=(const float*)d_in[6];  const float* ad1=(const float*)d_in[7];
  const float* We1=(const float*)d_in[8];  const float* ae1=(const float*)d_in[9];
  const float* te1=(const float*)d_in[10]; const float* Wo1=(const float*)d_in[11];
  const float* bo1=(const float*)d_in[12]; const float* b1 =(const float*)d_in[13];
  const float* lg1=(const float*)d_in[14]; const float* lb1=(const float*)d_in[15];
  const float* Ws2=(const float*)d_in[16]; const float* Wd2=(const float*)d_in[17];
  const float* as2=(const float*)d_in[18]; const float* ad2=(const float*)d_in[19];
  const float* We2=(const float*)d_in[20]; const float* ae2=(const float*)d_in[21];
  const float* te2=(const float*)d_in[22]; const float* Wo2=(const float*)d_in[23];
  const float* bo2=(const float*)d_in[24]; const float* b2 =(const float*)d_in[25];
  const float* lg2=(const float*)d_in[26]; const float* lb2=(const float*)d_in[27];
  const float* bng1=(const float*)d_in[28]; const float* bnb1=(const float*)d_in[29];
  const float* bng2=(const float*)d_in[30]; const float* bnb2=(const float*)d_in[31];

  char* p=(char*)d_ws;
  auto alloc=[&](size_t bytes)->void*{ void* r=(void*)p; p+=(bytes+255)&~(size_t)255; return r; };
  unsigned short* xb   =(unsigned short*)alloc((size_t)N*DD*2);
  unsigned short* ysb  =(unsigned short*)alloc((size_t)N*DD*2);
  unsigned short* aggb =(unsigned short*)alloc((size_t)N*DD*2);
  float* Sreg  =(float*)alloc((size_t)N*DD*4);        // alpha (Etot*8*4=10.9MB) then z (20.5MB)
  float* xout1 =(float*)alloc((size_t)N*DD*4);
  float* a_i   =(float*)alloc((size_t)N*HH*4);
  float* a_j   =(float*)alloc((size_t)N*HH*4);
  float* wd_as =(float*)alloc(DD*HH*4);
  float* v_e   =(float*)alloc(16*HH*4);
  float* t_a   =(float*)alloc(7*HH*4);
  float* colsum=(float*)alloc(256*4);
  float* colsq =(float*)alloc(256*4);
  float* scl   =(float*)alloc(256*4);
  float* shf   =(float*)alloc(256*4);
  unsigned short* Wsb1T=(unsigned short*)alloc((size_t)DD*DD*2);
  unsigned short* Wob1T=(unsigned short*)alloc((size_t)DD*DD*2);
  unsigned short* Wsb2T=(unsigned short*)alloc((size_t)DD*DD*2);
  unsigned short* Wob2T=(unsigned short*)alloc((size_t)DD*DD*2);
  int* cnt     =(int*)alloc((size_t)N*4);
  int* row_off =(int*)alloc((size_t)(N+1)*4);
  int* cursor  =(int*)alloc((size_t)N*4);
  int* eid     =(int*)alloc((size_t)Etot*4);
  int* esrc    =(int*)alloc((size_t)Etot*4);
  float* hbuf  =(float*)d_out;

  // upfront: CSR + weight transposes (bf16)
  k_zero_i<<<(N+255)/256,256,0,stream>>>(cnt,N);
  k_count<<<(Etot+255)/256,256,0,stream>>>(dstE,E,N,cnt);
  k_scan<<<1,1024,0,stream>>>(cnt,N,row_off,cursor);
  k_fill<<<(Etot+255)/256,256,0,stream>>>(srcE,dstE,E,N,cursor,eid,esrc);
  k_cvt_wT<<<DD,DD,0,stream>>>(Ws1,Wsb1T);
  k_cvt_wT<<<DD,DD,0,stream>>>(Wo1,Wob1T);
  k_cvt_wT<<<DD,DD,0,stream>>>(Ws2,Wsb2T);
  k_cvt_wT<<<DD,DD,0,stream>>>(Wo2,Wob2T);

  // layer 1
  run_layer(stream,N,E, x,srcE,dstE,ea,et,
            Wsb1T,Wd1,as1,ad1,We1,ae1,te1,Wob1T,bo1,b1,lg1,lb1,bng1,bnb1,
            row_off,eid,esrc,
            xb,ysb,aggb,Sreg,a_i,a_j,wd_as,v_e,t_a,colsum,colsq,scl,shf,
            hbuf,nullptr,xout1);

  // layer 2
  run_layer(stream,N,E, xout1,srcE,dstE,ea,et,
            Wsb2T,Wd2,as2,ad2,We2,ae2,te2,Wob2T,bo2,b2,lg2,lb2,bng2,bnb2,
            row_off,eid,esrc,
            xb,ysb,aggb,Sreg,a_i,a_j,wd_as,v_e,t_a,colsum,colsq,scl,shf,
            hbuf,x,(float*)d_out);
}

// Round 3
// 444.076 us; speedup vs baseline: 1.3334x; 1.0829x over previous
//
#include <hip/hip_runtime.h>

#define DD 256
#define HH 8
#define CC 32

typedef __attribute__((ext_vector_type(8))) short short8;
typedef __attribute__((ext_vector_type(4))) float f32x4;

static __device__ __forceinline__ unsigned short f2b(float f){
  unsigned u = __float_as_uint(f);
  u = u + 0x7FFFu + ((u >> 16) & 1u);          // RNE
  return (unsigned short)(u >> 16);
}
static __device__ __forceinline__ float b2f(unsigned short s){
  return __uint_as_float(((unsigned)s) << 16);
}

// ---------------- utility ----------------
__global__ void k_zero_i(int* p, int n){ int i=blockIdx.x*blockDim.x+threadIdx.x; if(i<n) p[i]=0; }
__global__ void k_zero_f(float* p, int n){ int i=blockIdx.x*blockDim.x+threadIdx.x; if(i<n) p[i]=0.f; }

// ---------------- CSR build ----------------
__global__ void k_count(const int* __restrict__ dstE, int E, int N, int* cnt){
  int e=blockIdx.x*blockDim.x+threadIdx.x;
  if(e<E+N){ int d=(e<E)? dstE[e] : (e-E); atomicAdd(&cnt[d],1); }
}

__global__ __launch_bounds__(1024) void k_scan(const int* __restrict__ cnt, int N, int* row_off, int* cursor){
  __shared__ int part[1024];
  int t=threadIdx.x;
  int chunk=(N+1023)>>10;
  int s=0;
  for(int j=0;j<chunk;j++){ int i=t*chunk+j; if(i<N) s+=cnt[i]; }
  part[t]=s; __syncthreads();
  for(int off=1; off<1024; off<<=1){
    int v=(t>=off)? part[t-off]:0;
    __syncthreads();
    part[t]+=v;
    __syncthreads();
  }
  int run=(t==0)?0:part[t-1];
  for(int j=0;j<chunk;j++){ int i=t*chunk+j; if(i<N){ row_off[i]=run; cursor[i]=run; run+=cnt[i]; } }
  if(t==1023) row_off[N]=part[1023];
}

__global__ void k_fill(const int* __restrict__ srcE, const int* __restrict__ dstE, int E, int N,
                       int* cursor, int* eid, int* esrc){
  int e=blockIdx.x*blockDim.x+threadIdx.x;
  if(e>=E+N) return;
  int s,d;
  if(e<E){ s=srcE[e]; d=dstE[e]; } else { s=e-E; d=s; }
  int pos=atomicAdd(&cursor[d],1);
  eid[pos]=e; esrc[pos]=s;
}

// ---------------- weight transpose + bf16 convert: Wt[c][k] = W[k][c] ----------------
__global__ void k_cvt_wT(const float* __restrict__ W, unsigned short* __restrict__ Wt){
  int c=blockIdx.x, k=threadIdx.x;
  Wt[(size_t)c*DD+k] = f2b(W[(size_t)k*DD+c]);
}

// ---------------- folded logit weights ----------------
__global__ void k_pre(const float* __restrict__ Wd, const float* __restrict__ as_,
                      const float* __restrict__ We, const float* __restrict__ ae,
                      const float* __restrict__ te,
                      float* wd_as, float* v_e, float* t_a){
  int t=threadIdx.x;
  for(int idx=t; idx<DD*HH; idx+=256){
    int k=idx>>3, h=idx&7;
    const float* w=&Wd[k*DD+h*CC]; const float* a=&as_[h*CC];
    float s=0;
    #pragma unroll
    for(int c=0;c<CC;c++) s+=w[c]*a[c];
    wd_as[idx]=s;
  }
  for(int idx=t; idx<16*HH; idx+=256){
    int k=idx>>3, h=idx&7;
    const float* w=&We[k*DD+h*CC]; const float* a=&ae[h*CC];
    float s=0;
    #pragma unroll
    for(int c=0;c<CC;c++) s+=w[c]*a[c];
    v_e[idx]=s;
  }
  for(int idx=t; idx<7*HH; idx+=256){
    int k=idx>>3, h=idx&7;
    const float* w=&te[k*DD+h*CC]; const float* a=&ae[h*CC];
    float s=0;
    #pragma unroll
    for(int c=0;c<CC;c++) s+=w[c]*a[c];
    t_a[idx]=s;
  }
}

// ---------------- x -> bf16 + a_i = x @ wd_as ----------------
__global__ __launch_bounds__(256) void k_cvt_x(const float* __restrict__ xin, const float* __restrict__ wd_as,
                        unsigned short* __restrict__ xb, float* __restrict__ a_i, int N){
  __shared__ float red[DD*HH];     // [k][h] 8KB
  __shared__ float part[8][8];
  int n=blockIdx.x, tid=threadIdx.x;
  float v=xin[(size_t)n*DD+tid];
  xb[(size_t)n*DD+tid]=f2b(v);
  #pragma unroll
  for(int h=0;h<HH;h++) red[tid*HH+h]=v*wd_as[tid*HH+h];
  __syncthreads();
  if(tid<64){
    int h=tid&7, ch=tid>>3;
    float s=0.f;
    for(int k=ch*32;k<ch*32+32;k++) s+=red[k*HH+h];
    part[ch][h]=s;
  }
  __syncthreads();
  if(tid<8){
    float s=0.f;
    #pragma unroll
    for(int ch=0;ch<8;ch++) s+=part[ch][tid];
    a_i[(size_t)n*HH+tid]=s;
  }
}

// ---------------- a_j[n,h] = sum_c ys[n,32h+c]*ad[h,c] (ys bf16) ----------------
__global__ void k_aj(const unsigned short* __restrict__ ysb, const float* __restrict__ ad,
                     float* __restrict__ a_j, int N){
  int n=blockIdx.x, tid=threadIdx.x;
  float p=b2f(ysb[(size_t)n*DD+tid])*ad[tid];
  #pragma unroll
  for(int off=16;off>0;off>>=1) p+=__shfl_xor(p,off);
  if((tid&31)==0) a_j[(size_t)n*HH+(tid>>5)]=p;
}

// ---------------- bf16 MFMA GEMM: C[N,256] = A_bf16[N,256] @ B (Bt = B^T bf16) ----------------
template<bool OUTBF16, bool BIAS>
__global__ __launch_bounds__(256) void k_gemm_mfma(const unsigned short* __restrict__ A,
                                                   const unsigned short* __restrict__ Bt,
                                                   const float* __restrict__ bia1, const float* __restrict__ bia2,
                                                   void* __restrict__ Cout, int N){
  __shared__ char lds[4096 + 8192];   // As 64x32 bf16 (4KB) + Bs 128x32 bf16 (8KB)
  int tid=threadIdx.x;
  int w=tid>>6, l=tid&63;
  int row0=blockIdx.y*64, col0=blockIdx.x*128;

  int sr=l>>2, skc=l&3;
  int arow=16*w+sr;
  int a_slot=arow*4+skc;
  int a_kc=skc^((arow>>1)&3);
  int grow=row0+arow;
  int bcol0=(2*w+0)*16+sr, bcol1=(2*w+1)*16+sr;
  int b_slot0=bcol0*4+skc, b_slot1=bcol1*4+skc;
  int b_kc0=skc^((bcol0>>1)&3), b_kc1=skc^((bcol1>>1)&3);

  int x15=l&15;
  int lp=x15*64 + ((l>>4)^((x15>>1)&3))*16;

  f32x4 acc[4][2];
  #pragma unroll
  for(int i=0;i<4;i++){ acc[i][0]=(f32x4)0.f; acc[i][1]=(f32x4)0.f; }

  const short8 zero8=(short8)0;
  for(int kt=0;kt<DD;kt+=32){
    short8 av = (grow<N) ? *(const short8*)&A[(size_t)grow*DD + kt + a_kc*8] : zero8;
    short8 bv0 = *(const short8*)&Bt[(size_t)(col0+bcol0)*DD + kt + b_kc0*8];
    short8 bv1 = *(const short8*)&Bt[(size_t)(col0+bcol1)*DD + kt + b_kc1*8];
    __syncthreads();
    *(short8*)(lds + a_slot*16) = av;
    *(short8*)(lds + 4096 + b_slot0*16) = bv0;
    *(short8*)(lds + 4096 + b_slot1*16) = bv1;
    __syncthreads();
    short8 af[4], bf[2];
    #pragma unroll
    for(int mf=0;mf<4;mf++) af[mf]=*(short8*)(lds + mf*1024 + lp);
    #pragma unroll
    for(int nf=0;nf<2;nf++) bf[nf]=*(short8*)(lds + 4096 + w*2048 + nf*1024 + lp);
    #pragma unroll
    for(int mf=0;mf<4;mf++)
      #pragma unroll
      for(int nf=0;nf<2;nf++)
        acc[mf][nf]=__builtin_amdgcn_mfma_f32_16x16x32_bf16(af[mf],bf[nf],acc[mf][nf],0,0,0);
  }

  int lcol=l&15, lrow4=(l>>4)*4;
  #pragma unroll
  for(int mf=0;mf<4;mf++){
    #pragma unroll
    for(int nf=0;nf<2;nf++){
      int col=col0 + 32*w + 16*nf + lcol;
      float badd = BIAS ? (bia1[col]+bia2[col]) : 0.f;
      #pragma unroll
      for(int rr=0;rr<4;rr++){
        int row=row0 + 16*mf + lrow4 + rr;
        if(row<N){
          float v=acc[mf][nf][rr]+badd;
          if(OUTBF16) ((unsigned short*)Cout)[(size_t)row*DD+col]=f2b(v);
          else        ((float*)Cout)[(size_t)row*DD+col]=v;
        }
      }
    }
  }
}

// ---------------- edge logits ----------------
__global__ void k_edge(const int* __restrict__ srcE, const int* __restrict__ dstE,
                       const float* __restrict__ ea, const int* __restrict__ et,
                       const float* __restrict__ a_i, const float* __restrict__ a_j,
                       const float* __restrict__ v_e, const float* __restrict__ t_a,
                       float* __restrict__ alpha, int E, int N){
  int e=blockIdx.x*blockDim.x+threadIdx.x;
  if(e>=E+N) return;
  int s,d,ty;
  float eattr[16];
  if(e<E){
    s=srcE[e]; d=dstE[e]; ty=et[e];
    #pragma unroll
    for(int k=0;k<16;k++) eattr[k]=ea[(size_t)e*16+k];
  }else{
    s=e-E; d=s; ty=6;
    #pragma unroll
    for(int k=0;k<16;k++) eattr[k]=1.f;
  }
  const float* ai=&a_i[(size_t)d*8];
  const float* aj=&a_j[(size_t)s*8];
  #pragma unroll
  for(int h=0;h<8;h++){
    float v=ai[h]+aj[h]+t_a[ty*8+h];
    #pragma unroll
    for(int k=0;k<16;k++) v+=eattr[k]*v_e[k*8+h];
    alpha[(size_t)e*8+h] = (v>=0.f)? v : 0.2f*v;
  }
}

// ---------------- segment softmax + aggregation: ONE WAVE PER NODE ----------------
// lane l: alpha phases use (edge-slot j=l>>3, head h=l&7); gather uses cols 4l..4l+3 (head l>>3).
__global__ __launch_bounds__(256) void k_agg(const int* __restrict__ row_off, const int* __restrict__ eid,
                      const int* __restrict__ esrc, const float* __restrict__ alpha,
                      const unsigned short* __restrict__ ysb, unsigned short* __restrict__ aggb, int N){
  int wv=threadIdx.x>>6, l=threadIdx.x&63;
  int n=blockIdx.x*4+wv;
  if(n>=N) return;
  int beg=row_off[n], deg=row_off[n+1]-beg;
  int j=l>>3, h=l&7;
  // pass 1: per-head max (slots reduce via butterfly over lane bits 3..5)
  float mx=-3e38f;
  for(int base=0;base<deg;base+=8){
    int i=base+j;
    if(i<deg) mx=fmaxf(mx, alpha[(size_t)eid[beg+i]*8+h]);
  }
  mx=fmaxf(mx,__shfl_xor(mx,8));
  mx=fmaxf(mx,__shfl_xor(mx,16));
  mx=fmaxf(mx,__shfl_xor(mx,32));
  // pass 2: exp + sum + unnormalized gather
  float ssum=0.f;
  float acc0=0.f,acc1=0.f,acc2=0.f,acc3=0.f;
  int ghead=l>>3;
  for(int base=0;base<deg;base+=8){
    int i=base+j;
    float wgt=0.f; int s=0;
    if(i<deg){
      wgt=__expf(alpha[(size_t)eid[beg+i]*8+h]-mx);
      s=esrc[beg+i];
    }
    ssum+=wgt;
    int cnt=min(8,deg-base);
    for(int ii=0;ii<cnt;ii++){
      float wi=__shfl(wgt,(ii<<3)|ghead);   // lane ii*8+ghead holds (edge base+ii, head ghead)
      int   si=__shfl(s,(ii<<3));           // lane ii*8 holds src of edge base+ii
      ushort4 y=*(const ushort4*)&ysb[(size_t)si*DD + 4*l];
      acc0+=wi*b2f(y.x); acc1+=wi*b2f(y.y); acc2+=wi*b2f(y.z); acc3+=wi*b2f(y.w);
    }
  }
  ssum+=__shfl_xor(ssum,8);
  ssum+=__shfl_xor(ssum,16);
  ssum+=__shfl_xor(ssum,32);
  float inv=1.f/(__shfl(ssum,ghead)+1e-16f);  // lane 'ghead' has h==ghead
  ushort4 o;
  o.x=f2b(acc0*inv); o.y=f2b(acc1*inv); o.z=f2b(acc2*inv); o.w=f2b(acc3*inv);
  *(ushort4*)&aggb[(size_t)n*DD+4*l]=o;
}

// ---------------- LayerNorm + residual ----------------
__global__ __launch_bounds__(256) void k_ln_res(const float* __restrict__ z, const float* __restrict__ xin,
                         const float* __restrict__ lg, const float* __restrict__ lb,
                         float* __restrict__ hout, int N){
  __shared__ float red[256];
  __shared__ float stats[2];
  int n=blockIdx.x, tid=threadIdx.x;
  float v=z[(size_t)n*DD+tid];
  red[tid]=v; __syncthreads();
  #pragma unroll
  for(int off=128; off>0; off>>=1){ if(tid<off) red[tid]+=red[tid+off]; __syncthreads(); }
  if(tid==0) stats[0]=red[0]*(1.f/DD);
  __syncthreads();
  float mu=stats[0], d=v-mu;
  red[tid]=d*d; __syncthreads();
  #pragma unroll
  for(int off=128; off>0; off>>=1){ if(tid<off) red[tid]+=red[tid+off]; __syncthreads(); }
  if(tid==0) stats[1]=rsqrtf(red[0]*(1.f/DD)+1e-5f);
  __syncthreads();
  hout[(size_t)n*DD+tid]=d*stats[1]*lg[tid]+lb[tid]+xin[(size_t)n*DD+tid];
}

// ---------------- BatchNorm ----------------
__global__ __launch_bounds__(256) void k_bnstat(const float* __restrict__ hm, float* colsum, float* colsq, int N){
  int col=threadIdx.x;
  int rows_per=(N+gridDim.x-1)/gridDim.x;
  int r0=blockIdx.x*rows_per, r1=min(N,r0+rows_per);
  float s=0.f,q=0.f;
  for(int r=r0;r<r1;r++){ float v=hm[(size_t)r*DD+col]; s+=v; q+=v*v; }
  atomicAdd(&colsum[col],s);
  atomicAdd(&colsq[col],q);
}

__global__ void k_bnfin(const float* __restrict__ colsum, const float* __restrict__ colsq,
                        const float* __restrict__ g, const float* __restrict__ b,
                        float* scale, float* shift, int N){
  int c=threadIdx.x;
  float inv=1.f/(float)N;
  float mu=colsum[c]*inv;
  float var=colsq[c]*inv - mu*mu;
  float sc=g[c]*rsqrtf(var+1e-5f);
  scale[c]=sc;
  shift[c]=b[c]-mu*sc;
}

// out = relu(h*scale + shift [+ res]); optionally also emit bf16 copy + next-layer a_i
template<bool RES, bool CVT>
__global__ __launch_bounds__(256) void k_bnapply(const float* __restrict__ hm, const float* __restrict__ scale,
                          const float* __restrict__ shift, const float* __restrict__ res,
                          float* __restrict__ outp, unsigned short* __restrict__ xb,
                          const float* __restrict__ wd_as, float* __restrict__ a_i, int N){
  __shared__ float red[DD*HH];
  __shared__ float part[8][8];
  int n=blockIdx.x, tid=threadIdx.x;
  float v=hm[(size_t)n*DD+tid]*scale[tid]+shift[tid];
  if(RES) v+=res[(size_t)n*DD+tid];
  v=fmaxf(v,0.f);
  outp[(size_t)n*DD+tid]=v;
  if(CVT){
    xb[(size_t)n*DD+tid]=f2b(v);
    #pragma unroll
    for(int h=0;h<HH;h++) red[tid*HH+h]=v*wd_as[tid*HH+h];
    __syncthreads();
    if(tid<64){
      int h=tid&7, ch=tid>>3;
      float s=0.f;
      for(int k=ch*32;k<ch*32+32;k++) s+=red[k*HH+h];
      part[ch][h]=s;
    }
    __syncthreads();
    if(tid<8){
      float s=0.f;
      #pragma unroll
      for(int ch=0;ch<8;ch++) s+=part[ch][tid];
      a_i[(size_t)n*HH+tid]=s;
    }
  }
}

extern "C" void kernel_launch(void* const* d_in, const int* in_sizes, int n_in,
                              void* d_out, int out_size, void* d_ws, size_t ws_size,
                              hipStream_t stream) {
  const float* x  = (const float*)d_in[0];
  const int*   ei = (const int*)d_in[1];
  const float* ea = (const float*)d_in[2];
  const int*   et = (const int*)d_in[3];
  int N = in_sizes[0]/DD;
  int E = in_sizes[3];
  int Etot = E+N;
  const int* srcE = ei;
  const int* dstE = ei + E;

  const float* Ws1=(const float*)d_in[4];  const float* Wd1=(const float*)d_in[5];
  const float* as1=(const float*)d_in[6];  const float* ad1=(const float*)d_in[7];
  const float* We1=(const float*)d_in[8];  const float* ae1=(const float*)d_in[9];
  const float* te1=(const float*)d_in[10]; const float* Wo1=(const float*)d_in[11];
  const float* bo1=(const float*)d_in[12]; const float* b1 =(const float*)d_in[13];
  const float* lg1=(const float*)d_in[14]; const float* lb1=(const float*)d_in[15];
  const float* Ws2=(const float*)d_in[16]; const float* Wd2=(const float*)d_in[17];
  const float* as2=(const float*)d_in[18]; const float* ad2=(const float*)d_in[19];
  const float* We2=(const float*)d_in[20]; const float* ae2=(const float*)d_in[21];
  const float* te2=(const float*)d_in[22]; const float* Wo2=(const float*)d_in[23];
  const float* bo2=(const float*)d_in[24]; const float* b2 =(const float*)d_in[25];
  const float* lg2=(const float*)d_in[26]; const float* lb2=(const float*)d_in[27];
  const float* bng1=(const float*)d_in[28]; const float* bnb1=(const float*)d_in[29];
  const float* bng2=(const float*)d_in[30]; const float* bnb2=(const float*)d_in[31];

  char* p=(char*)d_ws;
  auto alloc=[&](size_t bytes)->void*{ void* r=(void*)p; p+=(bytes+255)&~(size_t)255; return r; };
  unsigned short* xb   =(unsigned short*)alloc((size_t)N*DD*2);
  unsigned short* ysb  =(unsigned short*)alloc((size_t)N*DD*2);
  unsigned short* aggb =(unsigned short*)alloc((size_t)N*DD*2);
  float* Sreg  =(float*)alloc((size_t)N*DD*4);        // alpha (Etot*8*4=10.9MB) then z (20.5MB)
  float* xout1 =(float*)alloc((size_t)N*DD*4);
  float* a_i   =(float*)alloc((size_t)N*HH*4);
  float* a_j   =(float*)alloc((size_t)N*HH*4);
  float* wd_as1=(float*)alloc(DD*HH*4);
  float* v_e1  =(float*)alloc(16*HH*4);
  float* t_a1  =(float*)alloc(7*HH*4);
  float* wd_as2=(float*)alloc(DD*HH*4);
  float* v_e2  =(float*)alloc(16*HH*4);
  float* t_a2  =(float*)alloc(7*HH*4);
  float* colsum=(float*)alloc(256*4);
  float* colsq =(float*)alloc(256*4);
  float* scl   =(float*)alloc(256*4);
  float* shf   =(float*)alloc(256*4);
  unsigned short* Wsb1T=(unsigned short*)alloc((size_t)DD*DD*2);
  unsigned short* Wob1T=(unsigned short*)alloc((size_t)DD*DD*2);
  unsigned short* Wsb2T=(unsigned short*)alloc((size_t)DD*DD*2);
  unsigned short* Wob2T=(unsigned short*)alloc((size_t)DD*DD*2);
  int* cnt     =(int*)alloc((size_t)N*4);
  int* row_off =(int*)alloc((size_t)(N+1)*4);
  int* cursor  =(int*)alloc((size_t)N*4);
  int* eid     =(int*)alloc((size_t)Etot*4);
  int* esrc    =(int*)alloc((size_t)Etot*4);
  float* hbuf  =(float*)d_out;
  float* alphaBuf=Sreg;
  float* zbuf=Sreg;

  dim3 gg(2,(N+63)/64);
  int aggGrid=(N+3)/4;

  // upfront: CSR + weight prep (both layers)
  k_zero_i<<<(N+255)/256,256,0,stream>>>(cnt,N);
  k_count<<<(Etot+255)/256,256,0,stream>>>(dstE,E,N,cnt);
  k_scan<<<1,1024,0,stream>>>(cnt,N,row_off,cursor);
  k_fill<<<(Etot+255)/256,256,0,stream>>>(srcE,dstE,E,N,cursor,eid,esrc);
  k_cvt_wT<<<DD,DD,0,stream>>>(Ws1,Wsb1T);
  k_cvt_wT<<<DD,DD,0,stream>>>(Wo1,Wob1T);
  k_cvt_wT<<<DD,DD,0,stream>>>(Ws2,Wsb2T);
  k_cvt_wT<<<DD,DD,0,stream>>>(Wo2,Wob2T);
  k_pre<<<1,256,0,stream>>>(Wd1,as1,We1,ae1,te1,wd_as1,v_e1,t_a1);
  k_pre<<<1,256,0,stream>>>(Wd2,as2,We2,ae2,te2,wd_as2,v_e2,t_a2);

  // ---- layer 1 ----
  k_cvt_x<<<N,256,0,stream>>>(x,wd_as1,xb,a_i,N);
  k_gemm_mfma<true,false><<<gg,256,0,stream>>>(xb,Wsb1T,nullptr,nullptr,(void*)ysb,N);
  k_aj<<<N,256,0,stream>>>(ysb,ad1,a_j,N);
  k_edge<<<(Etot+255)/256,256,0,stream>>>(srcE,dstE,ea,et,a_i,a_j,v_e1,t_a1,alphaBuf,E,N);
  k_agg<<<aggGrid,256,0,stream>>>(row_off,eid,esrc,alphaBuf,ysb,aggb,N);
  k_gemm_mfma<false,true><<<gg,256,0,stream>>>(aggb,Wob1T,bo1,b1,(void*)zbuf,N);
  k_ln_res<<<N,256,0,stream>>>(zbuf,x,lg1,lb1,hbuf,N);
  k_zero_f<<<2,256,0,stream>>>(colsum,512);
  k_bnstat<<<256,256,0,stream>>>(hbuf,colsum,colsq,N);
  k_bnfin<<<1,256,0,stream>>>(colsum,colsq,bng1,bnb1,scl,shf,N);
  // fused: BN-apply + relu -> xout1 (f32) + xb (bf16) + a_i for layer 2
  k_bnapply<false,true><<<N,256,0,stream>>>(hbuf,scl,shf,nullptr,xout1,xb,wd_as2,a_i,N);

  // ---- layer 2 ----
  k_gemm_mfma<true,false><<<gg,256,0,stream>>>(xb,Wsb2T,nullptr,nullptr,(void*)ysb,N);
  k_aj<<<N,256,0,stream>>>(ysb,ad2,a_j,N);
  k_edge<<<(Etot+255)/256,256,0,stream>>>(srcE,dstE,ea,et,a_i,a_j,v_e2,t_a2,alphaBuf,E,N);
  k_agg<<<aggGrid,256,0,stream>>>(row_off,eid,esrc,alphaBuf,ysb,aggb,N);
  k_gemm_mfma<false,true><<<gg,256,0,stream>>>(aggb,Wob2T,bo2,b2,(void*)zbuf,N);
  k_ln_res<<<N,256,0,stream>>>(zbuf,xout1,lg2,lb2,hbuf,N);
  k_zero_f<<<2,256,0,stream>>>(colsum,512);
  k_bnstat<<<256,256,0,stream>>>(hbuf,colsum,colsq,N);
  k_bnfin<<<1,256,0,stream>>>(colsum,colsq,bng2,bnb2,scl,shf,N);
  k_bnapply<true,false><<<N,256,0,stream>>>(hbuf,scl,shf,x,(float*)d_out,nullptr,nullptr,nullptr,N);
}

// Round 4
// 440.498 us; speedup vs baseline: 1.3442x; 1.0081x over previous
//
#include <hip/hip_runtime.h>

#define DD 256
#define HH 8
#define CC 32

typedef __attribute__((ext_vector_type(8))) short short8;
typedef __attribute__((ext_vector_type(4))) float f32x4;

static __device__ __forceinline__ unsigned short f2b(float f){
  unsigned u = __float_as_uint(f);
  u = u + 0x7FFFu + ((u >> 16) & 1u);          // RNE
  return (unsigned short)(u >> 16);
}
static __device__ __forceinline__ float b2f(unsigned short s){
  return __uint_as_float(((unsigned)s) << 16);
}

// ---------------- utility ----------------
__global__ void k_zero_i(int* p, int n){ int i=blockIdx.x*blockDim.x+threadIdx.x; if(i<n) p[i]=0; }
__global__ void k_zero_f(float* p, int n){ int i=blockIdx.x*blockDim.x+threadIdx.x; if(i<n) p[i]=0.f; }

// ---------------- CSR build ----------------
__global__ void k_count(const int* __restrict__ dstE, int E, int N, int* cnt){
  int e=blockIdx.x*blockDim.x+threadIdx.x;
  if(e<E+N){ int d=(e<E)? dstE[e] : (e-E); atomicAdd(&cnt[d],1); }
}

__global__ __launch_bounds__(1024) void k_scan(const int* __restrict__ cnt, int N, int* row_off, int* cursor){
  __shared__ int part[1024];
  int t=threadIdx.x;
  int chunk=(N+1023)>>10;
  int s=0;
  for(int j=0;j<chunk;j++){ int i=t*chunk+j; if(i<N) s+=cnt[i]; }
  part[t]=s; __syncthreads();
  for(int off=1; off<1024; off<<=1){
    int v=(t>=off)? part[t-off]:0;
    __syncthreads();
    part[t]+=v;
    __syncthreads();
  }
  int run=(t==0)?0:part[t-1];
  for(int j=0;j<chunk;j++){ int i=t*chunk+j; if(i<N){ row_off[i]=run; cursor[i]=run; run+=cnt[i]; } }
  if(t==1023) row_off[N]=part[1023];
}

// emits e->pos mapping (epos) and CSR-ordered sources (esrc)
__global__ void k_fill(const int* __restrict__ srcE, const int* __restrict__ dstE, int E, int N,
                       int* cursor, int* epos, int* esrc){
  int e=blockIdx.x*blockDim.x+threadIdx.x;
  if(e>=E+N) return;
  int s,d;
  if(e<E){ s=srcE[e]; d=dstE[e]; } else { s=e-E; d=s; }
  int pos=atomicAdd(&cursor[d],1);
  epos[e]=pos; esrc[pos]=s;
}

// ---------------- weight transpose + bf16 convert: Wt[c][k] = W[k][c] ----------------
__global__ void k_cvt_wT(const float* __restrict__ W, unsigned short* __restrict__ Wt){
  int c=blockIdx.x, k=threadIdx.x;
  Wt[(size_t)c*DD+k] = f2b(W[(size_t)k*DD+c]);
}

// ---------------- folded logit weights ----------------
__global__ void k_pre(const float* __restrict__ Wd, const float* __restrict__ as_,
                      const float* __restrict__ We, const float* __restrict__ ae,
                      const float* __restrict__ te,
                      float* wd_as, float* v_e, float* t_a){
  int t=threadIdx.x;
  for(int idx=t; idx<DD*HH; idx+=256){
    int k=idx>>3, h=idx&7;
    const float* w=&Wd[k*DD+h*CC]; const float* a=&as_[h*CC];
    float s=0;
    #pragma unroll
    for(int c=0;c<CC;c++) s+=w[c]*a[c];
    wd_as[idx]=s;
  }
  for(int idx=t; idx<16*HH; idx+=256){
    int k=idx>>3, h=idx&7;
    const float* w=&We[k*DD+h*CC]; const float* a=&ae[h*CC];
    float s=0;
    #pragma unroll
    for(int c=0;c<CC;c++) s+=w[c]*a[c];
    v_e[idx]=s;
  }
  for(int idx=t; idx<7*HH; idx+=256){
    int k=idx>>3, h=idx&7;
    const float* w=&te[k*DD+h*CC]; const float* a=&ae[h*CC];
    float s=0;
    #pragma unroll
    for(int c=0;c<CC;c++) s+=w[c]*a[c];
    t_a[idx]=s;
  }
}

// ---------------- x -> bf16 + a_i = x @ wd_as ----------------
__global__ __launch_bounds__(256) void k_cvt_x(const float* __restrict__ xin, const float* __restrict__ wd_as,
                        unsigned short* __restrict__ xb, float* __restrict__ a_i, int N){
  __shared__ float red[DD*HH];     // [k][h] 8KB
  __shared__ float part[8][8];
  int n=blockIdx.x, tid=threadIdx.x;
  float v=xin[(size_t)n*DD+tid];
  xb[(size_t)n*DD+tid]=f2b(v);
  #pragma unroll
  for(int h=0;h<HH;h++) red[tid*HH+h]=v*wd_as[tid*HH+h];
  __syncthreads();
  if(tid<64){
    int h=tid&7, ch=tid>>3;
    float s=0.f;
    for(int k=ch*32;k<ch*32+32;k++) s+=red[k*HH+h];
    part[ch][h]=s;
  }
  __syncthreads();
  if(tid<8){
    float s=0.f;
    #pragma unroll
    for(int ch=0;ch<8;ch++) s+=part[ch][tid];
    a_i[(size_t)n*HH+tid]=s;
  }
}

// ---------------- a_j[n,h] = sum_c ys[n,32h+c]*ad[h,c] (ys bf16) ----------------
__global__ void k_aj(const unsigned short* __restrict__ ysb, const float* __restrict__ ad,
                     float* __restrict__ a_j, int N){
  int n=blockIdx.x, tid=threadIdx.x;
  float p=b2f(ysb[(size_t)n*DD+tid])*ad[tid];
  #pragma unroll
  for(int off=16;off>0;off>>=1) p+=__shfl_xor(p,off);
  if((tid&31)==0) a_j[(size_t)n*HH+(tid>>5)]=p;
}

// ---------------- bf16 MFMA GEMM: C[N,256] = A_bf16[N,256] @ B (Bt = B^T bf16) ----------------
// tile 128x128, BK=32, 4 waves; wave w -> 64x64 quadrant (wr=w>>1, wc=w&1), 4x4 MFMA frags.
// LDS: 16B granules; (row r, granule kc) data stored at slot r*4 + (kc ^ ((r>>1)&3)).
template<bool OUTBF16, bool BIAS>
__global__ __launch_bounds__(256) void k_gemm_mfma(const unsigned short* __restrict__ A,
                                                   const unsigned short* __restrict__ Bt,
                                                   const float* __restrict__ bia1, const float* __restrict__ bia2,
                                                   void* __restrict__ Cout, int N){
  __shared__ char lds[16384];   // As 128x32 (8KB) + Bs 128x32 (8KB)
  int tid=threadIdx.x;
  int w=tid>>6, l=tid&63;
  int wr=w>>1, wc=w&1;
  int row0=blockIdx.y*128, col0=blockIdx.x*128;

  // staging: thread t -> (r=t>>2, kc=t&3); handles rows r and r+64 (and same for B cols)
  int sr=tid>>2, skc=tid&3;
  int kcs=skc^((sr>>1)&3);             // source granule ((sr+64) has same xor factor: +32 even)
  int slot1=sr*4+skc, slot2=(sr+64)*4+skc;
  int gr1=row0+sr, gr2=row0+64+sr;
  size_t boff1=(size_t)(col0+sr)*DD, boff2=(size_t)(col0+64+sr)*DD;

  // frag read offset within a 16-row region
  int x15=l&15;
  int lp=x15*64 + ((l>>4)^((x15>>1)&3))*16;

  f32x4 acc[4][4];
  #pragma unroll
  for(int i=0;i<4;i++)
    #pragma unroll
    for(int jj=0;jj<4;jj++) acc[i][jj]=(f32x4)0.f;

  const short8 zero8=(short8)0;
  for(int kt=0;kt<DD;kt+=32){
    short8 av1 = (gr1<N) ? *(const short8*)&A[(size_t)gr1*DD + kt + kcs*8] : zero8;
    short8 av2 = (gr2<N) ? *(const short8*)&A[(size_t)gr2*DD + kt + kcs*8] : zero8;
    short8 bv1 = *(const short8*)&Bt[boff1 + kt + kcs*8];
    short8 bv2 = *(const short8*)&Bt[boff2 + kt + kcs*8];
    __syncthreads();
    *(short8*)(lds + slot1*16) = av1;
    *(short8*)(lds + slot2*16) = av2;
    *(short8*)(lds + 8192 + slot1*16) = bv1;
    *(short8*)(lds + 8192 + slot2*16) = bv2;
    __syncthreads();
    short8 af[4], bf[4];
    #pragma unroll
    for(int mf=0;mf<4;mf++) af[mf]=*(short8*)(lds + (64*wr+16*mf)*64 + lp);
    #pragma unroll
    for(int nf=0;nf<4;nf++) bf[nf]=*(short8*)(lds + 8192 + (64*wc+16*nf)*64 + lp);
    #pragma unroll
    for(int mf=0;mf<4;mf++)
      #pragma unroll
      for(int nf=0;nf<4;nf++)
        acc[mf][nf]=__builtin_amdgcn_mfma_f32_16x16x32_bf16(af[mf],bf[nf],acc[mf][nf],0,0,0);
  }

  int lcol=l&15, lrow4=(l>>4)*4;
  #pragma unroll
  for(int mf=0;mf<4;mf++){
    #pragma unroll
    for(int nf=0;nf<4;nf++){
      int col=col0 + 64*wc + 16*nf + lcol;
      float badd = BIAS ? (bia1[col]+bia2[col]) : 0.f;
      #pragma unroll
      for(int rr=0;rr<4;rr++){
        int row=row0 + 64*wr + 16*mf + lrow4 + rr;
        if(row<N){
          float v=acc[mf][nf][rr]+badd;
          if(OUTBF16) ((unsigned short*)Cout)[(size_t)row*DD+col]=f2b(v);
          else        ((float*)Cout)[(size_t)row*DD+col]=v;
        }
      }
    }
  }
}

// ---------------- edge logits, written in CSR (dst-sorted) order ----------------
__global__ void k_edge(const int* __restrict__ srcE, const int* __restrict__ dstE,
                       const float* __restrict__ ea, const int* __restrict__ et,
                       const int* __restrict__ epos,
                       const float* __restrict__ a_i, const float* __restrict__ a_j,
                       const float* __restrict__ v_e, const float* __restrict__ t_a,
                       float* __restrict__ alphaP, int E, int N){
  int e=blockIdx.x*blockDim.x+threadIdx.x;
  if(e>=E+N) return;
  int s,d,ty;
  float eattr[16];
  if(e<E){
    s=srcE[e]; d=dstE[e]; ty=et[e];
    #pragma unroll
    for(int k=0;k<16;k++) eattr[k]=ea[(size_t)e*16+k];
  }else{
    s=e-E; d=s; ty=6;
    #pragma unroll
    for(int k=0;k<16;k++) eattr[k]=1.f;
  }
  int pos=epos[e];
  const float* ai=&a_i[(size_t)d*8];
  const float* aj=&a_j[(size_t)s*8];
  #pragma unroll
  for(int h=0;h<8;h++){
    float v=ai[h]+aj[h]+t_a[ty*8+h];
    #pragma unroll
    for(int k=0;k<16;k++) v+=eattr[k]*v_e[k*8+h];
    alphaP[(size_t)pos*8+h] = (v>=0.f)? v : 0.2f*v;
  }
}

// ---------------- segment softmax + aggregation: ONE WAVE PER NODE ----------------
// pass1: lane=(slot j=l>>3, head h=l&7), coalesced alphaP stream, butterfly max.
// pass2: all 64 lanes walk all edges (unroll 4); lane l covers cols 4l..4l+3 (head l>>3).
__global__ __launch_bounds__(256) void k_agg(const int* __restrict__ row_off,
                      const int* __restrict__ esrc, const float* __restrict__ alphaP,
                      const unsigned short* __restrict__ ysb, unsigned short* __restrict__ aggb, int N){
  int wv=threadIdx.x>>6, l=threadIdx.x&63;
  int n=blockIdx.x*4+wv;
  if(n>=N) return;
  int beg=row_off[n], deg=row_off[n+1]-beg;
  int j=l>>3, h=l&7;
  float mx=-3e38f;
  for(int i=j;i<deg;i+=8) mx=fmaxf(mx, alphaP[(size_t)(beg+i)*8+h]);
  mx=fmaxf(mx,__shfl_xor(mx,8));
  mx=fmaxf(mx,__shfl_xor(mx,16));
  mx=fmaxf(mx,__shfl_xor(mx,32));
  int ghead=l>>3;
  float m_g=__shfl(mx,ghead);          // lane 'ghead' holds the max for head ghead
  float ssum=0.f, acc0=0.f, acc1=0.f, acc2=0.f, acc3=0.f;
  const float* aph=&alphaP[(size_t)beg*8+ghead];
  const int* es=&esrc[beg];
  for(int base=0;base<deg;base+=4){
    #pragma unroll
    for(int u=0;u<4;u++){
      int i=base+u;
      bool ok=(i<deg);
      int ic=ok?i:0;
      float a=aph[(size_t)ic*8];
      int s=es[ic];
      float wgt=ok?__expf(a-m_g):0.f;
      ssum+=wgt;                        // identical across each 8-lane group -> per-head sum
      ushort4 y=*(const ushort4*)&ysb[(size_t)s*DD+4*l];
      acc0+=wgt*b2f(y.x); acc1+=wgt*b2f(y.y); acc2+=wgt*b2f(y.z); acc3+=wgt*b2f(y.w);
    }
  }
  float inv=1.f/(ssum+1e-16f);
  ushort4 o;
  o.x=f2b(acc0*inv); o.y=f2b(acc1*inv); o.z=f2b(acc2*inv); o.w=f2b(acc3*inv);
  *(ushort4*)&aggb[(size_t)n*DD+4*l]=o;
}

// ---------------- LayerNorm + residual ----------------
__global__ __launch_bounds__(256) void k_ln_res(const float* __restrict__ z, const float* __restrict__ xin,
                         const float* __restrict__ lg, const float* __restrict__ lb,
                         float* __restrict__ hout, int N){
  __shared__ float red[256];
  __shared__ float stats[2];
  int n=blockIdx.x, tid=threadIdx.x;
  float v=z[(size_t)n*DD+tid];
  red[tid]=v; __syncthreads();
  #pragma unroll
  for(int off=128; off>0; off>>=1){ if(tid<off) red[tid]+=red[tid+off]; __syncthreads(); }
  if(tid==0) stats[0]=red[0]*(1.f/DD);
  __syncthreads();
  float mu=stats[0], d=v-mu;
  red[tid]=d*d; __syncthreads();
  #pragma unroll
  for(int off=128; off>0; off>>=1){ if(tid<off) red[tid]+=red[tid+off]; __syncthreads(); }
  if(tid==0) stats[1]=rsqrtf(red[0]*(1.f/DD)+1e-5f);
  __syncthreads();
  hout[(size_t)n*DD+tid]=d*stats[1]*lg[tid]+lb[tid]+xin[(size_t)n*DD+tid];
}

// ---------------- BatchNorm ----------------
__global__ __launch_bounds__(256) void k_bnstat(const float* __restrict__ hm, float* colsum, float* colsq, int N){
  int col=threadIdx.x;
  int rows_per=(N+gridDim.x-1)/gridDim.x;
  int r0=blockIdx.x*rows_per, r1=min(N,r0+rows_per);
  float s=0.f,q=0.f;
  for(int r=r0;r<r1;r++){ float v=hm[(size_t)r*DD+col]; s+=v; q+=v*v; }
  atomicAdd(&colsum[col],s);
  atomicAdd(&colsq[col],q);
}

__global__ void k_bnfin(const float* __restrict__ colsum, const float* __restrict__ colsq,
                        const float* __restrict__ g, const float* __restrict__ b,
                        float* scale, float* shift, int N){
  int c=threadIdx.x;
  float inv=1.f/(float)N;
  float mu=colsum[c]*inv;
  float var=colsq[c]*inv - mu*mu;
  float sc=g[c]*rsqrtf(var+1e-5f);
  scale[c]=sc;
  shift[c]=b[c]-mu*sc;
}

// out = relu(h*scale + shift [+ res]); optionally also emit bf16 copy + next-layer a_i
template<bool RES, bool CVT>
__global__ __launch_bounds__(256) void k_bnapply(const float* __restrict__ hm, const float* __restrict__ scale,
                          const float* __restrict__ shift, const float* __restrict__ res,
                          float* __restrict__ outp, unsigned short* __restrict__ xb,
                          const float* __restrict__ wd_as, float* __restrict__ a_i, int N){
  __shared__ float red[DD*HH];
  __shared__ float part[8][8];
  int n=blockIdx.x, tid=threadIdx.x;
  float v=hm[(size_t)n*DD+tid]*scale[tid]+shift[tid];
  if(RES) v+=res[(size_t)n*DD+tid];
  v=fmaxf(v,0.f);
  outp[(size_t)n*DD+tid]=v;
  if(CVT){
    xb[(size_t)n*DD+tid]=f2b(v);
    #pragma unroll
    for(int h=0;h<HH;h++) red[tid*HH+h]=v*wd_as[tid*HH+h];
    __syncthreads();
    if(tid<64){
      int h=tid&7, ch=tid>>3;
      float s=0.f;
      for(int k=ch*32;k<ch*32+32;k++) s+=red[k*HH+h];
      part[ch][h]=s;
    }
    __syncthreads();
    if(tid<8){
      float s=0.f;
      #pragma unroll
      for(int ch=0;ch<8;ch++) s+=part[ch][tid];
      a_i[(size_t)n*HH+tid]=s;
    }
  }
}

extern "C" void kernel_launch(void* const* d_in, const int* in_sizes, int n_in,
                              void* d_out, int out_size, void* d_ws, size_t ws_size,
                              hipStream_t stream) {
  const float* x  = (const float*)d_in[0];
  const int*   ei = (const int*)d_in[1];
  const float* ea = (const float*)d_in[2];
  const int*   et = (const int*)d_in[3];
  int N = in_sizes[0]/DD;
  int E = in_sizes[3];
  int Etot = E+N;
  const int* srcE = ei;
  const int* dstE = ei + E;

  const float* Ws1=(const float*)d_in[4];  const float* Wd1=(const float*)d_in[5];
  const float* as1=(const float*)d_in[6];  const float* ad1=(const float*)d_in[7];
  const float* We1=(const float*)d_in[8];  const float* ae1=(const float*)d_in[9];
  const float* te1=(const float*)d_in[10]; const float* Wo1=(const float*)d_in[11];
  const float* bo1=(const float*)d_in[12]; const float* b1 =(const float*)d_in[13];
  const float* lg1=(const float*)d_in[14]; const float* lb1=(const float*)d_in[15];
  const float* Ws2=(const float*)d_in[16]; const float* Wd2=(const float*)d_in[17];
  const float* as2=(const float*)d_in[18]; const float* ad2=(const float*)d_in[19];
  const float* We2=(const float*)d_in[20]; const float* ae2=(const float*)d_in[21];
  const float* te2=(const float*)d_in[22]; const float* Wo2=(const float*)d_in[23];
  const float* bo2=(const float*)d_in[24]; const float* b2 =(const float*)d_in[25];
  const float* lg2=(const float*)d_in[26]; const float* lb2=(const float*)d_in[27];
  const float* bng1=(const float*)d_in[28]; const float* bnb1=(const float*)d_in[29];
  const float* bng2=(const float*)d_in[30]; const float* bnb2=(const float*)d_in[31];

  char* p=(char*)d_ws;
  auto alloc=[&](size_t bytes)->void*{ void* r=(void*)p; p+=(bytes+255)&~(size_t)255; return r; };
  unsigned short* xb   =(unsigned short*)alloc((size_t)N*DD*2);
  unsigned short* ysb  =(unsigned short*)alloc((size_t)N*DD*2);
  unsigned short* aggb =(unsigned short*)alloc((size_t)N*DD*2);
  float* Sreg  =(float*)alloc((size_t)N*DD*4);        // alphaP (Etot*8*4=10.9MB) then z (20.5MB)
  float* xout1 =(float*)alloc((size_t)N*DD*4);
  float* a_i   =(float*)alloc((size_t)N*HH*4);
  float* a_j   =(float*)alloc((size_t)N*HH*4);
  float* wd_as1=(float*)alloc(DD*HH*4);
  float* v_e1  =(float*)alloc(16*HH*4);
  float* t_a1  =(float*)alloc(7*HH*4);
  float* wd_as2=(float*)alloc(DD*HH*4);
  float* v_e2  =(float*)alloc(16*HH*4);
  float* t_a2  =(float*)alloc(7*HH*4);
  float* colsum=(float*)alloc(256*4);
  float* colsq =(float*)alloc(256*4);
  float* scl   =(float*)alloc(256*4);
  float* shf   =(float*)alloc(256*4);
  unsigned short* Wsb1T=(unsigned short*)alloc((size_t)DD*DD*2);
  unsigned short* Wob1T=(unsigned short*)alloc((size_t)DD*DD*2);
  unsigned short* Wsb2T=(unsigned short*)alloc((size_t)DD*DD*2);
  unsigned short* Wob2T=(unsigned short*)alloc((size_t)DD*DD*2);
  int* cnt     =(int*)alloc((size_t)N*4);
  int* row_off =(int*)alloc((size_t)(N+1)*4);
  int* cursor  =(int*)alloc((size_t)N*4);
  int* epos    =(int*)alloc((size_t)Etot*4);
  int* esrc    =(int*)alloc((size_t)Etot*4);
  float* hbuf  =(float*)d_out;
  float* alphaP=Sreg;
  float* zbuf=Sreg;

  dim3 gg(2,(N+127)/128);
  int aggGrid=(N+3)/4;

  // upfront: CSR + weight prep (both layers)
  k_zero_i<<<(N+255)/256,256,0,stream>>>(cnt,N);
  k_count<<<(Etot+255)/256,256,0,stream>>>(dstE,E,N,cnt);
  k_scan<<<1,1024,0,stream>>>(cnt,N,row_off,cursor);
  k_fill<<<(Etot+255)/256,256,0,stream>>>(srcE,dstE,E,N,cursor,epos,esrc);
  k_cvt_wT<<<DD,DD,0,stream>>>(Ws1,Wsb1T);
  k_cvt_wT<<<DD,DD,0,stream>>>(Wo1,Wob1T);
  k_cvt_wT<<<DD,DD,0,stream>>>(Ws2,Wsb2T);
  k_cvt_wT<<<DD,DD,0,stream>>>(Wo2,Wob2T);
  k_pre<<<1,256,0,stream>>>(Wd1,as1,We1,ae1,te1,wd_as1,v_e1,t_a1);
  k_pre<<<1,256,0,stream>>>(Wd2,as2,We2,ae2,te2,wd_as2,v_e2,t_a2);

  // ---- layer 1 ----
  k_cvt_x<<<N,256,0,stream>>>(x,wd_as1,xb,a_i,N);
  k_gemm_mfma<true,false><<<gg,256,0,stream>>>(xb,Wsb1T,nullptr,nullptr,(void*)ysb,N);
  k_aj<<<N,256,0,stream>>>(ysb,ad1,a_j,N);
  k_edge<<<(Etot+255)/256,256,0,stream>>>(srcE,dstE,ea,et,epos,a_i,a_j,v_e1,t_a1,alphaP,E,N);
  k_agg<<<aggGrid,256,0,stream>>>(row_off,esrc,alphaP,ysb,aggb,N);
  k_gemm_mfma<false,true><<<gg,256,0,stream>>>(aggb,Wob1T,bo1,b1,(void*)zbuf,N);
  k_ln_res<<<N,256,0,stream>>>(zbuf,x,lg1,lb1,hbuf,N);
  k_zero_f<<<2,256,0,stream>>>(colsum,512);
  k_bnstat<<<256,256,0,stream>>>(hbuf,colsum,colsq,N);
  k_bnfin<<<1,256,0,stream>>>(colsum,colsq,bng1,bnb1,scl,shf,N);
  k_bnapply<false,true><<<N,256,0,stream>>>(hbuf,scl,shf,nullptr,xout1,xb,wd_as2,a_i,N);

  // ---- layer 2 ----
  k_gemm_mfma<true,false><<<gg,256,0,stream>>>(xb,Wsb2T,nullptr,nullptr,(void*)ysb,N);
  k_aj<<<N,256,0,stream>>>(ysb,ad2,a_j,N);
  k_edge<<<(Etot+255)/256,256,0,stream>>>(srcE,dstE,ea,et,epos,a_i,a_j,v_e2,t_a2,alphaP,E,N);
  k_agg<<<aggGrid,256,0,stream>>>(row_off,esrc,alphaP,ysb,aggb,N);
  k_gemm_mfma<false,true><<<gg,256,0,stream>>>(aggb,Wob2T,bo2,b2,(void*)zbuf,N);
  k_ln_res<<<N,256,0,stream>>>(zbuf,xout1,lg2,lb2,hbuf,N);
  k_zero_f<<<2,256,0,stream>>>(colsum,512);
  k_bnstat<<<256,256,0,stream>>>(hbuf,colsum,colsq,N);
  k_bnfin<<<1,256,0,stream>>>(colsum,colsq,bng2,bnb2,scl,shf,N);
  k_bnapply<true,false><<<N,256,0,stream>>>(hbuf,scl,shf,x,(float*)d_out,nullptr,nullptr,nullptr,N);
}